// Round 3
// baseline (127.498 us; speedup 1.0000x reference)
//
#include <hip/hip_runtime.h>

// Problem constants (from reference)
constexpr int N_SAMPLES = 512;
constexpr int J_GENES   = 20000;
constexpr int P_COV     = 8;
constexpr int DIM       = J_GENES - 1;   // pivot=True: last logit column is 0
constexpr int BLOCK     = 256;
constexpr int TABLE_N   = 1024;          // lgamma(y+1) table, y in [0,1000]

// Gene-tiled decomposition: block owns CHUNK_G genes (4/thread), loops ROWS rows.
constexpr int CHUNK_G   = 1024;
constexpr int G_CHUNKS  = (J_GENES + CHUNK_G - 1) / CHUNK_G;   // 20
constexpr int ROWS      = 8;
constexpr int RGROUPS   = N_SAMPLES / ROWS;                    // 64

// ---------------------------------------------------------------------------
// ws layout (floats) — no repack, no atomic targets (distinct-slot partials):
//   rw   [J]            r = 1/softplus(phi)
//   kw   [J]            K = r*log(r) - lgamma(r)
//   ps   [512*20]       per-(row,chunk) partial sum(Y)
//   pe   [512*20]       per-(row,chunk) partial sum(exp(logit))
constexpr size_t WS_RW    = 0;
constexpr size_t WS_KW    = WS_RW + J_GENES;
constexpr size_t WS_PS    = WS_KW + J_GENES;
constexpr size_t WS_PE    = WS_PS + (size_t)N_SAMPLES * G_CHUNKS;
constexpr size_t WS_TOTAL = WS_PE + (size_t)N_SAMPLES * G_CHUNKS;   // floats

__device__ inline float wave_reduce_sum(float v) {
#pragma unroll
    for (int off = 32; off > 0; off >>= 1)
        v += __shfl_down(v, off, 64);
    return v;
}

// Stirling lgamma for z > 0.2; shift-by-2 for z<2 (abs err <= ~3e-6).
__device__ inline float lgamma_pos(float z) {
    float corr = 0.0f;
    if (z < 2.0f) {
        corr = -__logf(z * (z + 1.0f));
        z += 2.0f;
    }
    float lz  = __logf(z);
    float rz  = __builtin_amdgcn_rcpf(z);
    float rz2 = rz * rz;
    // 1/(12z) - 1/(360 z^3) + 1/(1260 z^5)
    float ser = rz * fmaf(rz2, fmaf(rz2, 7.9365079365e-4f, -2.7777777778e-3f),
                          8.3333333333e-2f);
    return fmaf(z - 0.5f, lz, 0.91893853320467274f - z + ser + corr);
}

// Load the per-gene logit constants (mu, beta columns) raw with guards.
__device__ inline void load_gene_consts(const float* __restrict__ mu,
                                        const float* __restrict__ beta,
                                        int j0, bool valid,
                                        float muv[4], float bv[P_COV][4]) {
#pragma unroll
    for (int i = 0; i < 4; ++i) {
        const int j = j0 + i;
        const bool in = valid && (j < DIM);
        muv[i] = in ? mu[j] : 0.0f;
#pragma unroll
        for (int p = 0; p < P_COV; ++p)
            bv[p][i] = in ? beta[p * DIM + j] : 0.0f;
    }
}

// ---------------------------------------------------------------------------
// K1 (phase A): per-(row,chunk) partials of s = sum(Y) and E = sum(exp(logit)).
// by==0 blocks additionally compute r/K tables for their chunk (prep fold) and
// zero the output scalar. No atomics: distinct partial slots.
__global__ __launch_bounds__(BLOCK) void phaseA_kernel(
    const float* __restrict__ mu, const float* __restrict__ beta,
    const float* __restrict__ phi, const float* __restrict__ X,
    const float* __restrict__ Y, float* __restrict__ ws,
    float* __restrict__ out) {
    const int t  = threadIdx.x;
    const int bx = blockIdx.x, by = blockIdx.y;
    const int j0 = bx * CHUNK_G + t * 4;
    const bool valid = j0 < J_GENES;        // 20000 % 4 == 0: whole quads

    if (by == 0) {
        if (bx == 0 && t == 0) out[0] = 0.0f;   // K2 atomicAdds into out
        if (valid) {
#pragma unroll
            for (int i = 0; i < 4; ++i) {
                const int j = j0 + i;
                float ph = phi[j];
                float sp = (ph > 20.0f) ? ph : log1pf(__expf(ph));  // softplus
                float r  = 1.0f / sp;
                float lr = -__logf(sp);                              // log(r)
                ws[WS_RW + j] = r;
                ws[WS_KW + j] = fmaf(r, lr, -lgamma_pos(r));
            }
        }
    }

    float muv[4], bv[P_COV][4];
    load_gene_consts(mu, beta, j0, valid, muv, bv);

    __shared__ float redS[2][4], redE[2][4];
    const int n0 = by * ROWS;

    for (int rr = 0; rr < ROWS; ++rr) {
        const int n = n0 + rr;
        float x[P_COV];
#pragma unroll
        for (int p = 0; p < P_COV; ++p) x[p] = X[n * P_COV + p];

        float sa = 0.0f, ea = 0.0f;
        if (valid) {
            float4 y4 = *(const float4*)(Y + (size_t)n * J_GENES + j0);
            float lg[4];
#pragma unroll
            for (int i = 0; i < 4; ++i) {
                float v = muv[i];
#pragma unroll
                for (int p = 0; p < P_COV; ++p) v = fmaf(x[p], bv[p][i], v);
                lg[i] = v;
            }
            sa = (y4.x + y4.y) + (y4.z + y4.w);
            ea = (__expf(lg[0]) + __expf(lg[1])) + (__expf(lg[2]) + __expf(lg[3]));
        }

        float vs = wave_reduce_sum(sa);
        float ve = wave_reduce_sum(ea);
        const int b = rr & 1;                 // double-buffer: 1 sync per row
        if ((t & 63) == 0) { redS[b][t >> 6] = vs; redE[b][t >> 6] = ve; }
        __syncthreads();
        if (t == 0) {
            ws[WS_PS + (size_t)n * G_CHUNKS + bx] =
                (redS[b][0] + redS[b][1]) + (redS[b][2] + redS[b][3]);
            ws[WS_PE + (size_t)n * G_CHUNKS + bx] =
                (redE[b][0] + redE[b][1]) + (redE[b][2] + redE[b][3]);
        }
    }
}

// ---------------------------------------------------------------------------
// K2 (phase B): NB log-likelihood.
// term = lgamma(y+r) - lgamma(y+1) + K - (y+r)*log(r+mean) + y*(log c + logit)
// with mean = c*exp(logit), c = s/E  (log(mean) needs no extra log).
__device__ inline float nb_elem(float y, float lg, float r, float K,
                                float c, float logc,
                                const float* __restrict__ tbl) {
    float mean = c * __expf(lg);
    float z    = y + r;
    float lrm  = __logf(r + mean);
    int   yi   = (int)(y + 0.5f);
    float lgy1 = (yi < TABLE_N) ? tbl[yi] : lgamma_pos(y + 1.0f);
    return (lgamma_pos(z) - lgy1 + K) + fmaf(-z, lrm, y * (logc + lg));
}

__global__ __launch_bounds__(BLOCK) void phaseB_kernel(
    const float* __restrict__ mu, const float* __restrict__ beta,
    const float* __restrict__ X, const float* __restrict__ Y,
    const float* __restrict__ ws_c, float* __restrict__ out) {
    const int t  = threadIdx.x;
    const int bx = blockIdx.x, by = blockIdx.y;
    const int j0 = bx * CHUNK_G + t * 4;
    const bool valid = j0 < J_GENES;
    const int n0 = by * ROWS;

    __shared__ __align__(16) float tbl[TABLE_N];
    __shared__ float shS[ROWS], shE[ROWS], shc[ROWS], shlc[ROWS];

    // Build lgamma(k+1) table in-LDS (no ws round-trip). k<2 -> exact 0.
#pragma unroll
    for (int i = 0; i < 4; ++i) {
        const int k = t * 4 + i;
        tbl[k] = (k < 2) ? 0.0f : lgamma_pos((float)k + 1.0f);
    }
    // Gather per-row s and E from the 20 partials each (16 threads).
    if (t < 2 * ROWS) {
        const int r = t & (ROWS - 1);
        const int which = t >> 3;
        const float* src = ws_c + (which ? WS_PE : WS_PS)
                         + (size_t)(n0 + r) * G_CHUNKS;
        float a = 0.0f;
#pragma unroll
        for (int k = 0; k < G_CHUNKS; ++k) a += src[k];
        if (which) shE[r] = a; else shS[r] = a;
    }
    __syncthreads();
    if (t < ROWS) {
        float c = shS[t] / shE[t];
        shc[t]  = c;
        shlc[t] = __logf(c);
    }

    // Per-gene constants (registers across the row loop).
    float muv[4], bv[P_COV][4];
    load_gene_consts(mu, beta, j0, valid, muv, bv);
    float4 r4 = make_float4(1.f, 1.f, 1.f, 1.f);
    float4 K4 = make_float4(0.f, 0.f, 0.f, 0.f);
    if (valid) {
        r4 = *(const float4*)(ws_c + WS_RW + j0);
        K4 = *(const float4*)(ws_c + WS_KW + j0);
    }
    __syncthreads();   // tbl + shc ready

    float acc = 0.0f;
    for (int rr = 0; rr < ROWS; ++rr) {
        const int n = n0 + rr;
        const float c = shc[rr], logc = shlc[rr];
        float x[P_COV];
#pragma unroll
        for (int p = 0; p < P_COV; ++p) x[p] = X[n * P_COV + p];

        if (valid) {
            float4 y4 = *(const float4*)(Y + (size_t)n * J_GENES + j0);
            float lg[4];
#pragma unroll
            for (int i = 0; i < 4; ++i) {
                float v = muv[i];
#pragma unroll
                for (int p = 0; p < P_COV; ++p) v = fmaf(x[p], bv[p][i], v);
                lg[i] = v;
            }
            acc += nb_elem(y4.x, lg[0], r4.x, K4.x, c, logc, tbl);
            acc += nb_elem(y4.y, lg[1], r4.y, K4.y, c, logc, tbl);
            acc += nb_elem(y4.z, lg[2], r4.z, K4.z, c, logc, tbl);
            acc += nb_elem(y4.w, lg[3], r4.w, K4.w, c, logc, tbl);
        }
    }

    float v = wave_reduce_sum(acc);
    __shared__ float red[4];
    if ((t & 63) == 0) red[t >> 6] = v;
    __syncthreads();
    if (t == 0)
        atomicAdd(out, (red[0] + red[1]) + (red[2] + red[3]));
}

// ---------------------------------------------------------------------------
// Fallback (ws too small): round-1 monolithic kernel, known-correct.
__global__ __launch_bounds__(BLOCK) void nb_mono(
    const float* __restrict__ mu, const float* __restrict__ beta,
    const float* __restrict__ phi, const float* __restrict__ X,
    const float* __restrict__ Y, float* __restrict__ out) {
    const int n = blockIdx.x;
    const int t = threadIdx.x;
    __shared__ float red[4];
    __shared__ float sh_s, sh_lse, sh_logs;
    float x[P_COV];
#pragma unroll
    for (int p = 0; p < P_COV; ++p) x[p] = X[n * P_COV + p];
    const float* yrow = Y + (size_t)n * J_GENES;
    float s_acc = 0.0f, e_acc = 0.0f;
    for (int j = t; j < J_GENES; j += BLOCK) {
        float logit = 0.0f;
        if (j < DIM) {
            logit = mu[j];
#pragma unroll
            for (int p = 0; p < P_COV; ++p)
                logit = fmaf(x[p], beta[p * DIM + j], logit);
        }
        s_acc += yrow[j];
        e_acc += __expf(logit);
    }
    float v = wave_reduce_sum(s_acc);
    if ((t & 63) == 0) red[t >> 6] = v;
    __syncthreads();
    if (t == 0) { float st = red[0]+red[1]+red[2]+red[3]; sh_s = st; sh_logs = __logf(st); }
    __syncthreads();
    v = wave_reduce_sum(e_acc);
    if ((t & 63) == 0) red[t >> 6] = v;
    __syncthreads();
    if (t == 0) sh_lse = __logf(red[0]+red[1]+red[2]+red[3]);
    __syncthreads();
    const float s = sh_s, logs = sh_logs, lse = sh_lse;
    float acc = 0.0f;
    for (int j = t; j < J_GENES; j += BLOCK) {
        float logit = 0.0f;
        if (j < DIM) {
            logit = mu[j];
#pragma unroll
            for (int p = 0; p < P_COV; ++p)
                logit = fmaf(x[p], beta[p * DIM + j], logit);
        }
        float ph = phi[j];
        float sp = (ph > 20.0f) ? ph : log1pf(__expf(ph));
        float r  = 1.0f / sp;
        float y  = yrow[j];
        float lp = logit - lse;
        float mean = s * __expf(lp);
        float lrm  = __logf(r + mean);
        acc += lgamma_pos(y + r) - lgamma_pos(r) - lgamma_pos(y + 1.0f)
             + fmaf(r, -__logf(sp) - lrm, y * ((logs + lp) - lrm));
    }
    v = wave_reduce_sum(acc);
    if ((t & 63) == 0) red[t >> 6] = v;
    __syncthreads();
    if (t == 0) atomicAdd(out, (red[0]+red[1])+(red[2]+red[3]));
}

__global__ void zero_out_kernel(float* __restrict__ out) { out[0] = 0.0f; }

// ---------------------------------------------------------------------------
extern "C" void kernel_launch(void* const* d_in, const int* in_sizes, int n_in,
                              void* d_out, int out_size, void* d_ws, size_t ws_size,
                              hipStream_t stream) {
    const float* mu   = (const float*)d_in[0];  // [DIM]
    const float* beta = (const float*)d_in[1];  // [P*DIM]
    const float* phi  = (const float*)d_in[2];  // [J]
    const float* X    = (const float*)d_in[3];  // [N,P]
    const float* Y    = (const float*)d_in[4];  // [N,J]
    float* out = (float*)d_out;
    float* ws  = (float*)d_ws;

    if (ws_size >= WS_TOTAL * sizeof(float)) {
        dim3 grid(G_CHUNKS, RGROUPS);
        phaseA_kernel<<<grid, BLOCK, 0, stream>>>(mu, beta, phi, X, Y, ws, out);
        phaseB_kernel<<<grid, BLOCK, 0, stream>>>(mu, beta, X, Y, ws, out);
    } else {
        zero_out_kernel<<<1, 1, 0, stream>>>(out);
        nb_mono<<<N_SAMPLES, BLOCK, 0, stream>>>(mu, beta, phi, X, Y, out);
    }
}